// Round 1
// 458.428 us; speedup vs baseline: 1.0109x; 1.0109x over previous
//
#include <hip/hip_runtime.h>

// ---------------------------------------------------------------------------
// BasicTransformerBlock on MI355X (gfx950).
// R10: latency-bound GEMM fix. rocprof: GEGLU GEMM at MfmaUtil 15%, HBM 8%,
// 0 bank conflicts -> barrier-drain latency is the stall (__syncthreads emits
// vmcnt(0) which drains the same-iteration prefetch). K-loop restructured to
// 3-buffer stage-ahead-2 pipeline with counted s_waitcnt vmcnt(L) + bare
// s_barrier (T3/T4 from the CDNA4 guide), setprio(1) around MFMA cluster.
// Same transform applied to attn2's K/V loop. MW: GEGLU 4->3 (48KB LDS),
// N=512 GEMMs 3->4 (36KB LDS allows 4 blocks/CU).
// ---------------------------------------------------------------------------

typedef _Float16 half8 __attribute__((ext_vector_type(8)));
typedef float f32x4 __attribute__((ext_vector_type(4)));

__device__ __forceinline__ f32x4 mfma16(half8 a, half8 b, f32x4 c) {
  return __builtin_amdgcn_mfma_f32_16x16x32_f16(a, b, c, 0, 0, 0);
}

__device__ __forceinline__ void gload16(const _Float16* g, _Float16* l) {
  __builtin_amdgcn_global_load_lds(
      (const __attribute__((address_space(1))) void*)g,
      (__attribute__((address_space(3))) void*)l, 16, 0, 0);
}

template <int N>
__device__ __forceinline__ void wait_vmcnt() {
  if constexpr (N == 0)
    asm volatile("s_waitcnt vmcnt(0)" ::: "memory");
  else if constexpr (N == 1)
    asm volatile("s_waitcnt vmcnt(1)" ::: "memory");
  else if constexpr (N == 2)
    asm volatile("s_waitcnt vmcnt(2)" ::: "memory");
  else if constexpr (N == 3)
    asm volatile("s_waitcnt vmcnt(3)" ::: "memory");
  else if constexpr (N == 4)
    asm volatile("s_waitcnt vmcnt(4)" ::: "memory");
  else
    static_assert(N <= 4, "add a case");
}

// ---------------- fused prep: 10 weight transposes + enc cvt + LN1 ---------
struct PrepArgs {
  const float* src[10];
  _Float16* dst[10];
  int K[10], N[10], base[10];
  const float* enc;
  _Float16* ench;
  int encBase, nEnc;
  const float* x;
  const float* ln1g;
  const float* ln1b;
  _Float16* hbuf;
  int lnBase;  // first block index of LN rows (8192 rows follow)
};

__global__ __launch_bounds__(256)
void prep_all(PrepArgs pa) {
  __shared__ float tile[32][33];
  const int bid = blockIdx.x;
  const int tx = threadIdx.x, ty = threadIdx.y;
  const int t = ty * 32 + tx;
  if (bid >= pa.lnBase) {
    // -------- LayerNorm1 row --------
    const int row = bid - pa.lnBase;
    const float* xr = pa.x + (size_t)row * 512;
    float v0 = xr[t], v1 = xr[t + 256];
    float s1 = v0 + v1, s2 = v0 * v0 + v1 * v1;
    #pragma unroll
    for (int m = 32; m >= 1; m >>= 1) {
      s1 += __shfl_xor(s1, m);
      s2 += __shfl_xor(s2, m);
    }
    __shared__ float red[8];
    if ((t & 63) == 0) { red[t >> 6] = s1; red[4 + (t >> 6)] = s2; }
    __syncthreads();
    s1 = red[0] + red[1] + red[2] + red[3];
    s2 = red[4] + red[5] + red[6] + red[7];
    const float mu = s1 * (1.0f / 512.0f);
    const float var = s2 * (1.0f / 512.0f) - mu * mu;
    const float rs = rsqrtf(var + 1e-5f);
    pa.hbuf[(size_t)row * 512 + t] =
        (_Float16)((v0 - mu) * rs * pa.ln1g[t] + pa.ln1b[t]);
    pa.hbuf[(size_t)row * 512 + t + 256] =
        (_Float16)((v1 - mu) * rs * pa.ln1g[t + 256] + pa.ln1b[t + 256]);
    return;
  }
  if (bid >= pa.encBase) {
    const int i = (bid - pa.encBase) * 256 + t;
    if (i < pa.nEnc) pa.ench[i] = (_Float16)pa.enc[i];
    return;
  }
  int mi = 0;
  #pragma unroll
  for (int j = 1; j < 10; j++)
    if (bid >= pa.base[j]) mi = j;
  const int K = pa.K[mi], N = pa.N[mi];
  const int rel = bid - pa.base[mi];
  const int ntiles = N >> 5;
  const int bx = rel % ntiles, by = rel / ntiles;
  const float* src = pa.src[mi];
  _Float16* dst = pa.dst[mi];
  const int n0 = bx * 32, k0 = by * 32;
  #pragma unroll
  for (int j = ty; j < 32; j += 8)
    tile[j][tx] = src[(size_t)(k0 + j) * N + n0 + tx];
  __syncthreads();
  #pragma unroll
  for (int j = ty; j < 32; j += 8)
    dst[(size_t)(n0 + j) * K + k0 + tx] = (_Float16)tile[tx][j];
}

// ---------------- V transpose: [b*S+s][h*64+d] -> [(bh*64)+d][s] -----------
__global__ __launch_bounds__(256)
void vt_kernel(const _Float16* __restrict__ src, _Float16* __restrict__ dst,
               int S, int srcStride, int dstStride) {
  __shared__ _Float16 tile[32][33];
  const int tx = threadIdx.x, ty = threadIdx.y;  // (32,8)
  const int s0 = blockIdx.x * 32, d0 = blockIdx.y * 32, bh = blockIdx.z;
  const int b = bh >> 3, h = bh & 7;
  const _Float16* sp = src + (size_t)b * S * srcStride + h * 64 + d0;
  #pragma unroll
  for (int j = ty; j < 32; j += 8) {
    int s = s0 + j; if (s >= S) s = S - 1;
    tile[j][tx] = sp[(size_t)s * srcStride + tx];
  }
  __syncthreads();
  _Float16* dp = dst + ((size_t)bh * 64 + d0) * dstStride + s0;
  #pragma unroll
  for (int j = ty; j < 32; j += 8)
    dp[(size_t)j * dstStride + tx] = tile[tx][j];
}

// ---------------- LayerNorm (row=512), fp32 in -> f16 out ------------------
__global__ __launch_bounds__(256)
void ln_kernel(const float* __restrict__ x, const float* __restrict__ g,
               const float* __restrict__ b, _Float16* __restrict__ out) {
  const int row = blockIdx.x, t = threadIdx.x;
  const float* xr = x + (size_t)row * 512;
  float v0 = xr[t], v1 = xr[t + 256];
  float s1 = v0 + v1, s2 = v0 * v0 + v1 * v1;
  #pragma unroll
  for (int m = 32; m >= 1; m >>= 1) {
    s1 += __shfl_xor(s1, m);
    s2 += __shfl_xor(s2, m);
  }
  __shared__ float red[8];
  if ((t & 63) == 0) { red[t >> 6] = s1; red[4 + (t >> 6)] = s2; }
  __syncthreads();
  s1 = red[0] + red[1] + red[2] + red[3];
  s2 = red[4] + red[5] + red[6] + red[7];
  const float mu = s1 * (1.0f / 512.0f);
  const float var = s2 * (1.0f / 512.0f) - mu * mu;
  const float rs = rsqrtf(var + 1e-5f);
  out[(size_t)row * 512 + t] = (_Float16)((v0 - mu) * rs * g[t] + b[t]);
  out[(size_t)row * 512 + t + 256] =
      (_Float16)((v1 - mu) * rs * g[t + 256] + b[t + 256]);
}

// ---------------- GEMM: C = A[M,K] @ BT[N,K]^T -----------------------------
// 3-buffer stage-ahead-2 pipeline, counted vmcnt, XCD swizzle.
// EPI 0: f16 store. EPI 1: Cf = resid + acc + bias (f32). EPI 2: GEGLU dual.
template <int EPI, int GWM, int GWN, int WM, int WN, int MW, int SWZ>
__global__ __launch_bounds__(256, MW)
void gemm_bt(const _Float16* __restrict__ A, const _Float16* __restrict__ BT,
             int M, int N, int K, int lda, int ldc,
             _Float16* Ch, float* Cf,
             const float* __restrict__ bias, const float* resid) {
  constexpr int BM = GWM * WM * 16;
  constexpr int BN = GWN * WN * 16;
  // per-thread global_load_lds issued per stage (uniform across threads)
  constexpr int LPT = BM / 64 + BN / 64 + ((EPI == 2) ? BN / 64 : 0);
  __shared__ __align__(16) _Float16 As[3][4 * BM * 8];
  __shared__ __align__(16) _Float16 Bs[3][4 * BN * 8];
  __shared__ __align__(16) _Float16 Bs2[(EPI == 2) ? 3 : 1]
                                      [(EPI == 2) ? 4 * BN * 8 : 8];

  const int t = threadIdx.x;
  const int NNB = (N + BN - 1) / BN;
  int bm, bn;
  if constexpr (SWZ) {
    const int MG = (M / BM) >> 3;
    const int xcd = blockIdx.x & 7;
    const int s = blockIdx.x >> 3;
    bm = xcd * MG + s % MG;
    bn = s / MG;
  } else {
    bn = blockIdx.x % NNB;
    bm = blockIdx.x / NNB;
  }
  const int m0 = bm * BM, n0 = bn * BN;
  const int lane = t & 63, wv = t >> 6;
  const int quad = lane >> 4, l15 = lane & 15;
  const int wm = wv / GWN, wn = wv % GWN;

  f32x4 zero4 = {0.f, 0.f, 0.f, 0.f};
  f32x4 acc[WM][WN];
  f32x4 acc2[(EPI == 2) ? WM : 1][(EPI == 2) ? WN : 1];
  #pragma unroll
  for (int mi = 0; mi < WM; mi++)
    #pragma unroll
    for (int ni = 0; ni < WN; ni++) acc[mi][ni] = zero4;
  if constexpr (EPI == 2) {
    #pragma unroll
    for (int mi = 0; mi < WM; mi++)
      #pragma unroll
      for (int ni = 0; ni < WN; ni++) acc2[mi][ni] = zero4;
  }

  auto stageAll = [&](int k0, int pb) {
    #pragma unroll
    for (int c = wv; c < BM / 16; c += 4) {
      const int s = c * 64 + lane;
      const int q = s / BM;
      const int r = s % BM;
      int rg = m0 + r; if (rg >= M) rg = M - 1;
      gload16(A + (size_t)rg * lda + k0 + q * 8, &As[pb][c * 512]);
    }
    #pragma unroll
    for (int c = wv; c < BN / 16; c += 4) {
      const int s = c * 64 + lane;
      const int q = s / BN;
      const int r = s % BN;
      gload16(BT + (size_t)(n0 + r) * K + k0 + q * 8, &Bs[pb][c * 512]);
      if constexpr (EPI == 2)
        gload16(BT + (size_t)(2048 + n0 + r) * K + k0 + q * 8,
                &Bs2[pb][c * 512]);
    }
  };

  const int NIT = K >> 5;
  stageAll(0, 0);
  if (NIT > 1) stageAll(32, 1);

  int cur = 0, pre = 2;
  for (int it = 0; it < NIT; ++it) {
    // tile `it` must be resident: retire the oldest stage, keep the newest
    // in flight across the barrier (counted vmcnt, never 0 in steady state).
    if (it + 1 < NIT) wait_vmcnt<LPT>();
    else wait_vmcnt<0>();
    __builtin_amdgcn_s_barrier();
    __builtin_amdgcn_sched_barrier(0);

    half8 fa[WM], fb[WN], fb2[(EPI == 2) ? WN : 1];
    #pragma unroll
    for (int mi = 0; mi < WM; mi++)
      fa[mi] = *(const half8*)(&As[cur]
          [((size_t)quad * BM + wm * WM * 16 + mi * 16 + l15) * 8]);
    #pragma unroll
    for (int ni = 0; ni < WN; ni++) {
      fb[ni] = *(const half8*)(&Bs[cur]
          [((size_t)quad * BN + wn * WN * 16 + ni * 16 + l15) * 8]);
      if constexpr (EPI == 2)
        fb2[ni] = *(const half8*)(&Bs2[cur]
            [((size_t)quad * BN + wn * WN * 16 + ni * 16 + l15) * 8]);
    }
    __builtin_amdgcn_s_setprio(1);
    #pragma unroll
    for (int mi = 0; mi < WM; mi++)
      #pragma unroll
      for (int ni = 0; ni < WN; ni++) {
        acc[mi][ni] = mfma16(fa[mi], fb[ni], acc[mi][ni]);
        if constexpr (EPI == 2)
          acc2[mi][ni] = mfma16(fa[mi], fb2[ni], acc2[mi][ni]);
      }
    __builtin_amdgcn_s_setprio(0);
    // all my ds_reads of buf[cur] retired before signalling; fence the bare
    // barrier against compiler memory reordering (guide rule #18).
    asm volatile("s_waitcnt lgkmcnt(0)" ::: "memory");
    __builtin_amdgcn_sched_barrier(0);
    __builtin_amdgcn_s_barrier();
    if (it + 2 < NIT) stageAll((it + 2) << 5, pre);
    cur = (cur == 2) ? 0 : cur + 1;
    pre = (pre == 2) ? 0 : pre + 1;
  }

  #pragma unroll
  for (int mi = 0; mi < WM; mi++) {
    const int rbase = m0 + wm * WM * 16 + mi * 16 + quad * 4;
    #pragma unroll
    for (int r = 0; r < 4; r++) {
      const int row = rbase + r;
      if (row >= M) continue;
      #pragma unroll
      for (int ni = 0; ni < WN; ni++) {
        const int col = n0 + wn * WN * 16 + ni * 16 + l15;
        const float v = acc[mi][ni][r];
        if constexpr (EPI == 0) {
          Ch[(size_t)row * ldc + col] = (_Float16)v;
        } else if constexpr (EPI == 1) {
          Cf[(size_t)row * ldc + col] =
              resid[(size_t)row * ldc + col] + v + bias[col];
        } else {
          const float u = v + bias[col];
          const float gg = acc2[mi][ni][r] + bias[col + 2048];
          const float ge = 0.5f * gg * (1.0f + erff(gg * 0.70710678118f));
          Ch[(size_t)row * ldc + col] = (_Float16)(u * ge);
        }
      }
    }
  }
}

// ---------------- flash attention v2, 3-buffer counted-vmcnt pipeline ------
__global__ __launch_bounds__(256)
void attn2(const _Float16* __restrict__ Q, const _Float16* __restrict__ K,
           const _Float16* __restrict__ VT, _Float16* __restrict__ O,
           int qStride, int kStride, long kBatchStride,
           int vtStride, int Sk) {
  __shared__ __align__(16) _Float16 KsL[3][2048];
  __shared__ __align__(16) _Float16 VTsL[3][2048];
  __shared__ __align__(16) _Float16 Ps[4][2][16][40];

  const int t = threadIdx.x;
  const int w = t >> 6, lane = t & 63, quad = lane >> 4, l15 = lane & 15;
  const int bh = blockIdx.y, b = bh >> 3, h = bh & 7;
  const int q0 = blockIdx.x * 128 + w * 32;

  const _Float16 qscale = (_Float16)(0.125f * 1.44269504f);
  half8 qf[2][2];
  #pragma unroll
  for (int mi = 0; mi < 2; mi++)
    #pragma unroll
    for (int c = 0; c < 2; c++) {
      const _Float16* qp = Q +
          (size_t)(b * 1024 + q0 + mi * 16 + l15) * qStride +
          h * 64 + c * 32 + quad * 8;
      half8 v = *(const half8*)qp;
      #pragma unroll
      for (int j = 0; j < 8; j++) v[j] *= qscale;
      qf[mi][c] = v;
    }

  f32x4 zero4 = {0.f, 0.f, 0.f, 0.f};
  f32x4 oa[2][4];
  float psum[2][4];
  #pragma unroll
  for (int mi = 0; mi < 2; mi++) {
    #pragma unroll
    for (int nt = 0; nt < 4; nt++) oa[mi][nt] = zero4;
    #pragma unroll
    for (int r = 0; r < 4; r++) psum[mi][r] = 0.f;
  }

  const _Float16* kp = K + (size_t)b * kBatchStride + h * 64;
  const _Float16* vtp = VT + (size_t)bh * 64 * vtStride;
  const int ksk = t & 31, kc = t >> 7, kqd = (t >> 5) & 3;
  const int vd = t & 63, vqd = t >> 6;

  auto stageKV = [&](int skb, int pb) {
    int skc = skb + ksk; if (skc >= Sk) skc = Sk - 1;
    gload16(kp + (size_t)skc * kStride + kc * 32 + kqd * 8, &KsL[pb][t * 8]);
    gload16(vtp + (size_t)vd * vtStride + skb + vqd * 8, &VTsL[pb][t * 8]);
  };

  const int NITa = (Sk + 31) >> 5;
  stageKV(0, 0);
  if (NITa > 1) stageKV(32, 1);

  int cur = 0, pre = 2;
  int it = 0;
  for (int skb = 0; skb < Sk; skb += 32, ++it) {
    if (it + 1 < NITa) wait_vmcnt<2>();
    else wait_vmcnt<0>();
    __builtin_amdgcn_s_barrier();
    __builtin_amdgcn_sched_barrier(0);

    const bool tail = (skb + 32 > Sk);
    #pragma unroll
    for (int mi = 0; mi < 2; mi++) {
      #pragma unroll
      for (int ct = 0; ct < 2; ct++) {
        f32x4 s = zero4;
        half8 kb0 = *(const half8*)(&KsL[cur][(quad * 32 + ct * 16 + l15) * 8]);
        half8 kb1 =
            *(const half8*)(&KsL[cur][(128 + quad * 32 + ct * 16 + l15) * 8]);
        s = mfma16(qf[mi][0], kb0, s);
        s = mfma16(qf[mi][1], kb1, s);
        if (tail) {
          const bool valid = (skb + ct * 16 + l15) < Sk;
          #pragma unroll
          for (int r = 0; r < 4; r++)
            if (!valid) s[r] = -__builtin_inff();
        }
        #pragma unroll
        for (int r = 0; r < 4; r++) {
          const float e = exp2f(s[r]);
          psum[mi][r] += e;
          Ps[w][mi][quad * 4 + r][ct * 16 + l15] = (_Float16)e;
        }
      }
    }
    #pragma unroll
    for (int mi = 0; mi < 2; mi++) {
      const half8 pf = *(const half8*)(&Ps[w][mi][l15][quad * 8]);
      #pragma unroll
      for (int nt = 0; nt < 4; nt++) {
        const half8 vf =
            *(const half8*)(&VTsL[cur][(quad * 64 + nt * 16 + l15) * 8]);
        oa[mi][nt] = mfma16(pf, vf, oa[mi][nt]);
      }
    }

    asm volatile("s_waitcnt lgkmcnt(0)" ::: "memory");
    __builtin_amdgcn_sched_barrier(0);
    __builtin_amdgcn_s_barrier();
    if (it + 2 < NITa) stageKV(skb + 64, pre);
    cur = (cur == 2) ? 0 : cur + 1;
    pre = (pre == 2) ? 0 : pre + 1;
  }

  #pragma unroll
  for (int mi = 0; mi < 2; mi++)
    #pragma unroll
    for (int r = 0; r < 4; r++) {
      #pragma unroll
      for (int mm = 1; mm < 16; mm <<= 1)
        psum[mi][r] += __shfl_xor(psum[mi][r], mm);
      psum[mi][r] = 1.0f / psum[mi][r];
    }

  #pragma unroll
  for (int mi = 0; mi < 2; mi++)
    #pragma unroll
    for (int nt = 0; nt < 4; nt++)
      #pragma unroll
      for (int r = 0; r < 4; r++) {
        const size_t row = (size_t)(b * 1024 + q0 + mi * 16 + quad * 4 + r);
        O[row * 512 + h * 64 + nt * 16 + l15] =
            (_Float16)(oa[mi][nt][r] * psum[mi][r]);
      }
}

// ---------------------------------------------------------------------------
extern "C" void kernel_launch(void* const* d_in, const int* in_sizes, int n_in,
                              void* d_out, int out_size, void* d_ws,
                              size_t ws_size, hipStream_t stream) {
  const float* x    = (const float*)d_in[0];
  const float* enc  = (const float*)d_in[1];
  const float* ln1g = (const float*)d_in[2];
  const float* ln1b = (const float*)d_in[3];
  const float* wq1  = (const float*)d_in[4];
  const float* wk1  = (const float*)d_in[5];
  const float* wv1  = (const float*)d_in[6];
  const float* wo1  = (const float*)d_in[7];
  const float* bo1  = (const float*)d_in[8];
  const float* ln2g = (const float*)d_in[9];
  const float* ln2b = (const float*)d_in[10];
  const float* wq2  = (const float*)d_in[11];
  const float* wk2  = (const float*)d_in[12];
  const float* wv2  = (const float*)d_in[13];
  const float* wo2  = (const float*)d_in[14];
  const float* bo2  = (const float*)d_in[15];
  const float* ln3g = (const float*)d_in[16];
  const float* ln3b = (const float*)d_in[17];
  const float* wg   = (const float*)d_in[18];
  const float* bg   = (const float*)d_in[19];
  const float* wf   = (const float*)d_in[20];
  const float* bfp  = (const float*)d_in[21];
  float* out = (float*)d_out;

  char* ws = (char*)d_ws;
  _Float16* qkvT  = (_Float16*)(ws + 0);         // [1536,512]
  _Float16* q2T   = (_Float16*)(ws + 1572864);   // [512,512]
  _Float16* kv2T  = (_Float16*)(ws + 2097152);   // [1024,768]
  _Float16* wo1T  = (_Float16*)(ws + 3670016);   // [512,512]
  _Float16* wo2T  = (_Float16*)(ws + 4194304);   // [512,512]
  _Float16* wgT   = (_Float16*)(ws + 4718592);   // [4096,512]
  _Float16* wfT   = (_Float16*)(ws + 8912896);   // [512,2048]
  _Float16* hbuf  = (_Float16*)(ws + 11010048);  // [8192,512] (VTself in attn1)
  _Float16* qkv   = (_Float16*)(ws + 19398656);  // [8192,1536]
  _Float16* q2b   = (_Float16*)(ws + 44564480);  // [8192,512]
  _Float16* kv2b  = (_Float16*)(ws + 52953088);  // [616,1024]
  _Float16* attnb = (_Float16*)(ws + 54214656);  // [8192,512]
  _Float16* ench  = (_Float16*)(ws + 62603264);  // [616,768]
  _Float16* ffb   = (_Float16*)(ws + 19398656);  // [8192,2048] aliases qkv+q2b
  _Float16* VTself = hbuf;                       // [4096,1024]
  _Float16* VTc   = (_Float16*)(ws + 62603264);  // [4096,96] over ench (dead
                                                 // after kv2 GEMM)

  // ---- fused prep: weights + enc + LN1 (one launch) ----
  PrepArgs pa;
  const float* srcs[10] = {wq1, wk1, wv1, wo1, wq2, wk2, wv2, wo2, wg, wf};
  _Float16* dsts[10] = {qkvT, qkvT + 512 * 512, qkvT + 1024 * 512, wo1T, q2T,
                        kv2T, kv2T + 512 * 768, wo2T, wgT, wfT};
  const int Ks[10] = {512, 512, 512, 512, 512, 768, 768, 512, 512, 2048};
  const int Ns[10] = {512, 512, 512, 512, 512, 512, 512, 512, 4096, 512};
  int base = 0;
  for (int i = 0; i < 10; i++) {
    pa.src[i] = srcs[i]; pa.dst[i] = dsts[i];
    pa.K[i] = Ks[i]; pa.N[i] = Ns[i]; pa.base[i] = base;
    base += (Ks[i] >> 5) * (Ns[i] >> 5);
  }
  pa.enc = enc; pa.ench = ench; pa.encBase = base; pa.nEnc = 473088;
  base += (473088 + 255) / 256;
  pa.x = x; pa.ln1g = ln1g; pa.ln1b = ln1b; pa.hbuf = hbuf; pa.lnBase = base;
  base += 8192;
  prep_all<<<base, dim3(32, 8), 0, stream>>>(pa);

  const dim3 tb(32, 8);

  // ---- self-attention block ----
  gemm_bt<0, 2, 2, 4, 4, 3, 1><<<768, 256, 0, stream>>>(
      hbuf, qkvT, 8192, 1536, 512, 512, 1536, qkv, nullptr, nullptr, nullptr);
  vt_kernel<<<dim3(32, 2, 64), tb, 0, stream>>>(qkv + 1024, VTself, 1024,
                                                1536, 1024);
  attn2<<<dim3(8, 64), 256, 0, stream>>>(qkv, qkv + 512, VTself, attnb,
                                         1536, 1536, (long)1024 * 1536,
                                         1024, 1024);
  gemm_bt<1, 1, 4, 4, 2, 4, 1><<<512, 256, 0, stream>>>(
      attnb, wo1T, 8192, 512, 512, 512, 512, nullptr, out, bo1, x);

  // ---- cross-attention block ----
  ln_kernel<<<8192, 256, 0, stream>>>(out, ln2g, ln2b, hbuf);
  gemm_bt<0, 1, 4, 4, 2, 4, 1><<<512, 256, 0, stream>>>(
      hbuf, q2T, 8192, 512, 512, 512, 512, q2b, nullptr, nullptr, nullptr);
  gemm_bt<0, 1, 4, 4, 2, 4, 0><<<80, 256, 0, stream>>>(
      ench, kv2T, 616, 1024, 768, 768, 1024, kv2b, nullptr, nullptr, nullptr);
  vt_kernel<<<dim3(3, 2, 64), tb, 0, stream>>>(kv2b + 512, VTc, 77, 1024, 96);
  attn2<<<dim3(8, 64), 256, 0, stream>>>(q2b, kv2b, VTc, attnb,
                                         512, 1024, (long)77 * 1024, 96, 77);
  gemm_bt<1, 1, 4, 4, 2, 4, 1><<<512, 256, 0, stream>>>(
      attnb, wo2T, 8192, 512, 512, 512, 512, nullptr, out, bo2, out);

  // ---- GEGLU feed-forward ----
  ln_kernel<<<8192, 256, 0, stream>>>(out, ln3g, ln3b, hbuf);
  gemm_bt<2, 2, 2, 4, 2, 3, 1><<<2048, 256, 0, stream>>>(
      hbuf, wgT, 8192, 2048, 512, 512, 2048, ffb, nullptr, bg, nullptr);
  gemm_bt<1, 1, 4, 4, 2, 4, 1><<<512, 256, 0, stream>>>(
      ffb, wfT, 8192, 512, 2048, 2048, 512, nullptr, out, bfp, out);
}